// Round 1
// baseline (943.983 us; speedup 1.0000x reference)
//
#include <hip/hip_runtime.h>

// Problem constants (also derived from in_sizes at launch):
//   N = 100000 rows/cols, C = 64 channels, E = 3.2M edges.
// out[r*64+ch] = b[ch] + sum_{edges (r,c)} W[ch][c],  r normalized by row.min().
//
// ws layout: [0..255]  int flags: [0]=isInt32, [1]=min(int32 interp), [2]=min(int64 interp)
//            [256.. ]  Wt transposed weights, N*64 floats (if ws_size permits)

__global__ void LINK_init_kernel(float* __restrict__ out, const float* __restrict__ b,
                                 int total, int* __restrict__ flags) {
    int i = blockIdx.x * blockDim.x + threadIdx.x;
    if (i == 0) { flags[0] = 0; flags[1] = 0x7fffffff; flags[2] = 0x7fffffff; }
    if (i < total) out[i] = b[i & 63];
}

// One pass over the first 2*E 32-bit words of edge_index (valid for both dtypes):
//  - oddOr: OR of odd-position words. int64 data -> 0 (high words of row values < 2^31).
//           int32 data -> nonzero (random row/col values at odd positions).
//  - mn32:  min over words[0..E)        (row array under int32 interpretation)
//  - mn64:  min over even words [0..2E) (row array low-words under int64 interpretation)
__global__ void LINK_analyze_kernel(const unsigned int* __restrict__ words, int E,
                                    int* __restrict__ flags) {
    long long stride = (long long)gridDim.x * blockDim.x;
    long long i0 = (long long)blockIdx.x * blockDim.x + threadIdx.x;
    long long twoE = 2LL * E;
    unsigned int oddOr = 0u;
    int mn32 = 0x7fffffff, mn64 = 0x7fffffff;
    for (long long i = i0; i < twoE; i += stride) {
        unsigned int w = words[i];
        if (i & 1) {
            oddOr |= w;
        } else {
            int v = (int)w;
            if (v < mn64) mn64 = v;
        }
        if (i < E) {
            int v = (int)w;
            if (v < mn32) mn32 = v;
        }
    }
    // wave-64 reduction
    for (int off = 32; off > 0; off >>= 1) {
        oddOr |= (unsigned int)__shfl_down((int)oddOr, off, 64);
        mn32 = min(mn32, __shfl_down(mn32, off, 64));
        mn64 = min(mn64, __shfl_down(mn64, off, 64));
    }
    if ((threadIdx.x & 63) == 0) {
        if (oddOr) atomicOr(&flags[0], 1);
        atomicMin(&flags[1], mn32);
        atomicMin(&flags[2], mn64);
    }
}

// W [64][N] -> Wt [N][64] via LDS 64x64 tile (padded, conflict-free), coalesced both ways.
__global__ void LINK_transpose_kernel(const float* __restrict__ W, float* __restrict__ Wt,
                                      int N) {
    __shared__ float tile[64][65];
    int n0 = blockIdx.x * 64;
    int lx = threadIdx.x & 63;
    int ly = threadIdx.x >> 6;  // 0..3
#pragma unroll
    for (int it = 0; it < 16; ++it) {
        int ch = ly + 4 * it;
        float v = 0.0f;
        if (n0 + lx < N) v = W[(size_t)ch * N + (n0 + lx)];
        tile[lx][ch] = v;
    }
    __syncthreads();
#pragma unroll
    for (int it = 0; it < 16; ++it) {
        int nn = ly + 4 * it;
        if (n0 + nn < N) Wt[(size_t)(n0 + nn) * 64 + lx] = tile[nn][lx];
    }
}

// One 64-lane group per edge; lane = channel. Coalesced 256B Wt read,
// coalesced 64-dword atomicAdd into the output row.
__global__ void LINK_scatter_kernel(const unsigned int* __restrict__ words, int E,
                                    const float* __restrict__ Wt,
                                    const float* __restrict__ W,
                                    float* __restrict__ out,
                                    const int* __restrict__ flags, int useWt, int N) {
    long long g = (long long)blockIdx.x * blockDim.x + threadIdx.x;
    int e = (int)(g >> 6);
    if (e >= E) return;
    int ch = (int)(g & 63);
    int isInt32 = flags[0];
    int r, c, rmin;
    if (isInt32) {
        r = (int)words[e];
        c = (int)words[E + e];
        rmin = flags[1];
    } else {
        r = (int)words[2LL * e];            // low word of int64 row
        c = (int)words[2LL * (E + e)];      // low word of int64 col
        rmin = flags[2];
    }
    r -= rmin;
    float v = useWt ? Wt[(size_t)c * 64 + ch] : W[(size_t)ch * N + c];
    atomicAdd(&out[(size_t)r * 64 + ch], v);
}

extern "C" void kernel_launch(void* const* d_in, const int* in_sizes, int n_in,
                              void* d_out, int out_size, void* d_ws, size_t ws_size,
                              hipStream_t stream) {
    const unsigned int* words = (const unsigned int*)d_in[0];
    const float* W = (const float*)d_in[1];
    const float* b = (const float*)d_in[2];
    float* out = (float*)d_out;

    int E = in_sizes[0] / 2;      // 3,200,000
    int N = in_sizes[1] / 64;     // 100,000
    int total = out_size;         // N*64 = 6,400,000

    int* flags = (int*)d_ws;
    float* Wt = (float*)((char*)d_ws + 256);
    size_t wt_bytes = 256 + (size_t)N * 64 * sizeof(float);
    int useWt = (ws_size >= wt_bytes) ? 1 : 0;

    LINK_init_kernel<<<(total + 255) / 256, 256, 0, stream>>>(out, b, total, flags);
    LINK_analyze_kernel<<<1024, 256, 0, stream>>>(words, E, flags);
    if (useWt) {
        LINK_transpose_kernel<<<(N + 63) / 64, 256, 0, stream>>>(W, Wt, N);
    }
    long long tthreads = (long long)E * 64;
    int blocks = (int)((tthreads + 255) / 256);
    LINK_scatter_kernel<<<blocks, 256, 0, stream>>>(words, E, Wt, W, out, flags, useWt, N);
}

// Round 2
// 626.871 us; speedup vs baseline: 1.5059x; 1.5059x over previous
//
#include <hip/hip_runtime.h>

// out[r*64+ch] = b[ch] + sum_{edges (r,c)} W[ch][c],  r normalized by row.min().
// N = 100000, C = 64, E = 3.2M.
//
// R2 strategy: padded-CSR counting sort (int atomics only) + per-row wave gather.
// ws layout (256B-aligned chunks):
//   flags[256 ints]: [0]=isInt32 [1]=min32 [2]=min64 [8]=ovfCount
//   cur  [N ints]  : tail pointers, init cur[i] = i*cap
//   Wt   [N*64 f32]: transposed weights
//   ovf  [OVF_MAX*2 ints]: spill list for rows exceeding cap
//   cols [N*cap ints]: padded per-row col lists

#define OVF_MAX (1 << 20)

__global__ void LINK_init_csr_kernel(int* __restrict__ cur, int* __restrict__ flags,
                                     int N, int cap) {
    int i = blockIdx.x * blockDim.x + threadIdx.x;
    if (i == 0) { flags[0] = 0; flags[1] = 0x7fffffff; flags[2] = 0x7fffffff; flags[8] = 0; }
    if (i < N) cur[i] = i * cap;
}

// Detect int32 vs int64 edge_index and compute row.min() under both interpretations.
__global__ void LINK_analyze_kernel(const unsigned int* __restrict__ words, int E,
                                    int* __restrict__ flags) {
    long long stride = (long long)gridDim.x * blockDim.x;
    long long i0 = (long long)blockIdx.x * blockDim.x + threadIdx.x;
    long long twoE = 2LL * E;
    unsigned int oddOr = 0u;
    int mn32 = 0x7fffffff, mn64 = 0x7fffffff;
    for (long long i = i0; i < twoE; i += stride) {
        unsigned int w = words[i];
        if (i & 1) oddOr |= w;
        else { int v = (int)w; if (v < mn64) mn64 = v; }
        if (i < E) { int v = (int)w; if (v < mn32) mn32 = v; }
    }
    for (int off = 32; off > 0; off >>= 1) {
        oddOr |= (unsigned int)__shfl_down((int)oddOr, off, 64);
        mn32 = min(mn32, __shfl_down(mn32, off, 64));
        mn64 = min(mn64, __shfl_down(mn64, off, 64));
    }
    if ((threadIdx.x & 63) == 0) {
        if (oddOr) atomicOr(&flags[0], 1);
        atomicMin(&flags[1], mn32);
        atomicMin(&flags[2], mn64);
    }
}

// W [64][N] -> Wt [N][64] via padded LDS tile.
__global__ void LINK_transpose_kernel(const float* __restrict__ W, float* __restrict__ Wt,
                                      int N) {
    __shared__ float tile[64][65];
    int n0 = blockIdx.x * 64;
    int lx = threadIdx.x & 63;
    int ly = threadIdx.x >> 6;
#pragma unroll
    for (int it = 0; it < 16; ++it) {
        int ch = ly + 4 * it;
        float v = 0.0f;
        if (n0 + lx < N) v = W[(size_t)ch * N + (n0 + lx)];
        tile[lx][ch] = v;
    }
    __syncthreads();
#pragma unroll
    for (int it = 0; it < 16; ++it) {
        int nn = ly + 4 * it;
        if (n0 + nn < N) Wt[(size_t)(n0 + nn) * 64 + lx] = tile[nn][lx];
    }
}

// One thread per edge: place col id into its row's padded slot.
__global__ void LINK_fill_kernel(const unsigned int* __restrict__ words, int E, int N,
                                 int* __restrict__ cur, int* __restrict__ cols,
                                 int* __restrict__ ovf, int* __restrict__ flags, int cap) {
    int e = blockIdx.x * blockDim.x + threadIdx.x;
    if (e >= E) return;
    int r, c;
    if (flags[0]) { r = (int)words[e]; c = (int)words[E + e]; }
    else          { r = (int)words[2LL * e]; c = (int)words[2LL * E + 2LL * e]; }
    if ((unsigned)r >= (unsigned)N || (unsigned)c >= (unsigned)N) return;
    int pos = atomicAdd(&cur[r], 1);
    int slot = pos - r * cap;
    if (slot < cap) {
        cols[pos] = c;
    } else {
        int oi = atomicAdd(&flags[8], 1);
        if (oi < OVF_MAX) { ovf[2 * oi] = r; ovf[2 * oi + 1] = c; }
    }
}

// One wave per output row; lane = channel. Coalesced 256B Wt gathers, no atomics.
__global__ void LINK_gather_kernel(const int* __restrict__ cur, const int* __restrict__ cols,
                                   const float* __restrict__ Wt, const float* __restrict__ b,
                                   float* __restrict__ out, const int* __restrict__ flags,
                                   int N, int cap) {
    int g = blockIdx.x * blockDim.x + threadIdx.x;
    int row = g >> 6;
    int lane = g & 63;
    if (row >= N) return;
    int rmin = flags[0] ? flags[1] : flags[2];
    float acc = 0.0f;
    long long raw = (long long)row + rmin;
    if (raw >= 0 && raw < N) {
        int base = (int)raw * cap;
        int len = cur[raw] - base;
        if (len > cap) len = cap;
        const int* cp = cols + base;
        int j = 0;
        for (; j + 4 <= len; j += 4) {
            int c0 = cp[j], c1 = cp[j + 1], c2 = cp[j + 2], c3 = cp[j + 3];
            float v0 = Wt[(size_t)c0 * 64 + lane];
            float v1 = Wt[(size_t)c1 * 64 + lane];
            float v2 = Wt[(size_t)c2 * 64 + lane];
            float v3 = Wt[(size_t)c3 * 64 + lane];
            acc += v0; acc += v1; acc += v2; acc += v3;
        }
        for (; j < len; ++j) acc += Wt[(size_t)cp[j] * 64 + lane];
    }
    out[(size_t)row * 64 + lane] = acc + b[lane];
}

// Cleanup for the (expected ~zero) spilled edges: wave per edge chunk, fp atomics.
__global__ void LINK_ovf_kernel(const int* __restrict__ ovf, const int* __restrict__ flags,
                                const float* __restrict__ Wt, float* __restrict__ out,
                                int N) {
    int g = blockIdx.x * blockDim.x + threadIdx.x;
    int w = g >> 6, lane = g & 63;
    int cnt = flags[8]; if (cnt > OVF_MAX) cnt = OVF_MAX;
    if (cnt == 0) return;
    int rmin = flags[0] ? flags[1] : flags[2];
    int nw = (gridDim.x * blockDim.x) >> 6;
    for (int i = w; i < cnt; i += nw) {
        int r = ovf[2 * i] - rmin;
        int c = ovf[2 * i + 1];
        if ((unsigned)r >= (unsigned)N) continue;
        atomicAdd(&out[(size_t)r * 64 + lane], Wt[(size_t)c * 64 + lane]);
    }
}

// ---- Fallback path (R1): bias-init + wave-per-edge fp-atomic scatter ----
__global__ void LINK_init_bias_kernel(float* __restrict__ out, const float* __restrict__ b,
                                      int total, int* __restrict__ flags) {
    int i = blockIdx.x * blockDim.x + threadIdx.x;
    if (i == 0) { flags[0] = 0; flags[1] = 0x7fffffff; flags[2] = 0x7fffffff; }
    if (i < total) out[i] = b[i & 63];
}

__global__ void LINK_scatter_kernel(const unsigned int* __restrict__ words, int E,
                                    const float* __restrict__ Wt,
                                    const float* __restrict__ W,
                                    float* __restrict__ out,
                                    const int* __restrict__ flags, int useWt, int N) {
    long long g = (long long)blockIdx.x * blockDim.x + threadIdx.x;
    int e = (int)(g >> 6);
    if (e >= E) return;
    int ch = (int)(g & 63);
    int r, c, rmin;
    if (flags[0]) { r = (int)words[e]; c = (int)words[E + e]; rmin = flags[1]; }
    else { r = (int)words[2LL * e]; c = (int)words[2LL * (E + e)]; rmin = flags[2]; }
    r -= rmin;
    if ((unsigned)r >= (unsigned)N || (unsigned)c >= (unsigned)N) return;
    float v = useWt ? Wt[(size_t)c * 64 + ch] : W[(size_t)ch * N + c];
    atomicAdd(&out[(size_t)r * 64 + ch], v);
}

static inline size_t align256(size_t x) { return (x + 255) & ~(size_t)255; }

extern "C" void kernel_launch(void* const* d_in, const int* in_sizes, int n_in,
                              void* d_out, int out_size, void* d_ws, size_t ws_size,
                              hipStream_t stream) {
    const unsigned int* words = (const unsigned int*)d_in[0];
    const float* W = (const float*)d_in[1];
    const float* b = (const float*)d_in[2];
    float* out = (float*)d_out;

    int E = in_sizes[0] / 2;   // 3,200,000 edges
    int N = in_sizes[1] / 64;  // 100,000 nodes
    int total = out_size;      // N*64

    // ws carve-up
    size_t off_flags = 0;
    size_t off_cur   = align256(off_flags + 256 * sizeof(int));
    size_t off_wt    = align256(off_cur + (size_t)N * sizeof(int));
    size_t off_ovf   = align256(off_wt + (size_t)N * 64 * sizeof(float));
    size_t off_cols  = align256(off_ovf + (size_t)OVF_MAX * 2 * sizeof(int));

    int* flags = (int*)((char*)d_ws + off_flags);
    int* cur   = (int*)((char*)d_ws + off_cur);
    float* Wt  = (float*)((char*)d_ws + off_wt);
    int* ovf   = (int*)((char*)d_ws + off_ovf);
    int* cols  = (int*)((char*)d_ws + off_cols);

    long long avail_cols = (ws_size > off_cols)
        ? (long long)((ws_size - off_cols) / ((size_t)N * sizeof(int))) : 0;
    int cap = (int)(avail_cols > 128 ? 128 : avail_cols);
    bool useCSR = (cap >= 48);

    if (useCSR) {
        LINK_init_csr_kernel<<<(N + 255) / 256, 256, 0, stream>>>(cur, flags, N, cap);
        LINK_analyze_kernel<<<1024, 256, 0, stream>>>(words, E, flags);
        LINK_transpose_kernel<<<(N + 63) / 64, 256, 0, stream>>>(W, Wt, N);
        LINK_fill_kernel<<<(E + 255) / 256, 256, 0, stream>>>(words, E, N, cur, cols, ovf,
                                                              flags, cap);
        long long gthreads = (long long)N * 64;
        LINK_gather_kernel<<<(int)((gthreads + 255) / 256), 256, 0, stream>>>(
            cur, cols, Wt, b, out, flags, N, cap);
        LINK_ovf_kernel<<<1024, 256, 0, stream>>>(ovf, flags, Wt, out, N);
    } else {
        // Fallback: R1 atomic-scatter path.
        size_t wt_bytes = off_wt + (size_t)N * 64 * sizeof(float);
        int useWt = (ws_size >= wt_bytes) ? 1 : 0;
        LINK_init_bias_kernel<<<(total + 255) / 256, 256, 0, stream>>>(out, b, total, flags);
        LINK_analyze_kernel<<<1024, 256, 0, stream>>>(words, E, flags);
        if (useWt) LINK_transpose_kernel<<<(N + 63) / 64, 256, 0, stream>>>(W, Wt, N);
        long long tthreads = (long long)E * 64;
        LINK_scatter_kernel<<<(int)((tthreads + 255) / 256), 256, 0, stream>>>(
            words, E, Wt, W, out, flags, useWt, N);
    }
}